// Round 5
// baseline (656.380 us; speedup 1.0000x reference)
//
#include <hip/hip_runtime.h>
#include <hip/hip_bf16.h>

typedef float f32x4 __attribute__((ext_vector_type(4)));
typedef __bf16 bf16x8 __attribute__((ext_vector_type(8)));

#define N_IMG 32
#define C_IN  256
#define HW    56
#define N_X   (N_IMG * C_IN * HW * HW)
#define HP    58
#define WPAD  68

static constexpr size_t WQ_OFF  = 8192;                 // bf16[256][2304]  [oc][tap][c]
static constexpr size_t XP_OFF  = 2097152;              // bf16[32][58][68][256]

__device__ __forceinline__ unsigned enc_f(float f) {
    unsigned u = __float_as_uint(f);
    return (u & 0x80000000u) ? ~u : (u | 0x80000000u);
}
__device__ __forceinline__ float dec_f(unsigned u) {
    u = (u & 0x80000000u) ? (u & 0x7FFFFFFFu) : ~u;
    return __uint_as_float(u);
}

__device__ __forceinline__ void gload16(void* lds, const void* g) {
    __builtin_amdgcn_global_load_lds(
        (const __attribute__((address_space(1))) unsigned int*)g,
        (__attribute__((address_space(3))) unsigned int*)lds, 16, 0, 0);
}

__global__ void k_init(unsigned* hdr) {
    int t = threadIdx.x;
    if (t == 0) hdr[0] = 0xFFFFFFFFu;
    if (t == 1) hdr[1] = 0u;
    if (t >= 4 && t < 20) hdr[t] = 0u;
}

__global__ __launch_bounds__(256) void k_minmax(const float4* __restrict__ x4, int n4, unsigned* hdr) {
    float mn = INFINITY, mx = -INFINITY;
    for (int i = blockIdx.x * blockDim.x + threadIdx.x; i < n4; i += gridDim.x * blockDim.x) {
        float4 v = x4[i];
        mn = fminf(mn, fminf(fminf(v.x, v.y), fminf(v.z, v.w)));
        mx = fmaxf(mx, fmaxf(fmaxf(v.x, v.y), fmaxf(v.z, v.w)));
    }
    for (int s = 32; s; s >>= 1) {
        mn = fminf(mn, __shfl_xor(mn, s));
        mx = fmaxf(mx, __shfl_xor(mx, s));
    }
    __shared__ float smn[4], smx[4];
    int l = threadIdx.x & 63, wv = threadIdx.x >> 6;
    if (l == 0) { smn[wv] = mn; smx[wv] = mx; }
    __syncthreads();
    if (threadIdx.x == 0) {
        mn = fminf(fminf(smn[0], smn[1]), fminf(smn[2], smn[3]));
        mx = fmaxf(fmaxf(smx[0], smx[1]), fmaxf(smx[2], smx[3]));
        atomicMin(&hdr[0], enc_f(mn));
        atomicMax(&hdr[1], enc_f(mx));
    }
}

__global__ void k_scalars(unsigned* hdr) {
    float xmin = dec_f(hdr[0]), xmax = dec_f(hdr[1]);
    float in_scale = (xmax - xmin) / 255.0f;
    float zp = rintf(-128.0f - xmin / in_scale);
    ((float*)hdr)[2] = in_scale;
    ((float*)hdr)[3] = zp;
}

__global__ __launch_bounds__(256) void k_wquant(const float* __restrict__ weight,
                                                const float* __restrict__ bias,
                                                const int* __restrict__ bits,
                                                char* ws) {
    float* hf = (float*)ws;
    __hip_bfloat16* Wq = (__hip_bfloat16*)(ws + WQ_OFF);
    int oc = blockIdx.x, tid = threadIdx.x;
    const float* wp = weight + ((size_t)oc * 256 + tid) * 9;
    float w9[9];
    float wm = 0.0f;
#pragma unroll
    for (int t = 0; t < 9; ++t) { w9[t] = wp[t]; wm = fmaxf(wm, fabsf(w9[t])); }
    for (int s = 32; s; s >>= 1) wm = fmaxf(wm, __shfl_xor(wm, s));
    __shared__ float red[4];
    __shared__ float s_wsc;
    int l = tid & 63, wv = tid >> 6;
    if (l == 0) red[wv] = wm;
    __syncthreads();
    int b = bits[oc];
    if (tid == 0) {
        float wmax = fmaxf(fmaxf(red[0], red[1]), fmaxf(red[2], red[3]));
        float qd = (float)((1 << b) - 1);
        float wsc = fmaxf(wmax * 2.0f / qd, 1e-9f);
        s_wsc = wsc;
        float in_scale = hf[2];
        hf[64 + oc] = rintf(bias[oc] / (in_scale * wsc));
    }
    __syncthreads();
    float wsc = s_wsc;
    float qmax = (float)((1 << (b - 1)) - 1);
    float qmin = -(float)(1 << (b - 1));
    size_t base = (size_t)oc * 2304;
#pragma unroll
    for (int t = 0; t < 9; ++t) {
        float q = rintf(w9[t] / wsc);
        q = fminf(fmaxf(q, qmin), qmax);
        Wq[base + t * 256 + tid] = __float2bfloat16(q);
    }
}

// quantize + NCHW -> padded NHWC bf16; writes all borders incl. wp 64..67, no memset
__global__ __launch_bounds__(256) void k_quantx(const float* __restrict__ x, char* ws) {
    const float* hf = (const float*)ws;
    float in_scale = hf[2], zp = hf[3];
    __hip_bfloat16* Xp = (__hip_bfloat16*)(ws + XP_OFF);
    int h = blockIdx.y, n = blockIdx.z;     // h is PADDED coord
    int tid = threadIdx.x;
    __shared__ float tx[32][65];
    int wA = tid & 63, cA = tid >> 6;      // read: 64 w x 4 c (one c per wave)
    int wW = tid >> 2, cq = tid & 3;       // write: 64 wp x 4 c-octs
    int xh = h - 1;
    bool hok = (xh >= 0 && xh < 56);
    int xw = wA - 1;
    bool ok = hok && (xw >= 0 && xw < 56);
    size_t rowbase = ((size_t)n * HP + h) * WPAD * 256;
    for (int ct = 0; ct < 8; ++ct) {
#pragma unroll
        for (int cs = 0; cs < 8; ++cs) {
            int c = ct * 32 + cs * 4 + cA;
            float q = 0.0f;
            if (ok) {
                float v = x[(((size_t)n * 256 + c) * 56 + xh) * 56 + xw];
                float xi = rintf(v / in_scale + zp);
                xi = fminf(fmaxf(xi, -128.0f), 127.0f);
                q = xi - zp;
            }
            tx[cs * 4 + cA][wA] = q;
        }
        __syncthreads();
        {
            __hip_bfloat16 tmp[8];
#pragma unroll
            for (int k2 = 0; k2 < 8; ++k2) tmp[k2] = __float2bfloat16(tx[cq * 8 + k2][wW]);
            *(uint4*)&Xp[rowbase + (size_t)wW * 256 + ct * 32 + cq * 8] = *(uint4*)tmp;
        }
        if (tid < 16) {   // zero-fill wp 64..67
            int wpz = 64 + (tid >> 2), cqz = tid & 3;
            uint4 z = {0, 0, 0, 0};
            *(uint4*)&Xp[rowbase + (size_t)wpz * 256 + ct * 32 + cqz * 8] = z;
        }
        __syncthreads();
    }
}

// conv: workgroup = 256 oc x 2 output rows; 4 waves = 2 oc-halves x 2 rows.
// K-loop: 4 iters of 64 c; X staged via global_load_lds (double-buffered, source-side
// XOR swizzle); weight fragments software-pipelined depth-1 in registers (afA/afB).
__global__ __launch_bounds__(256, 2) void k_conv(const int* __restrict__ bits,
                                                 float* __restrict__ out, char* ws) {
    const float* hf = (const float*)ws;
    unsigned* hdr = (unsigned*)ws;
    const __hip_bfloat16* Xp = (const __hip_bfloat16*)(ws + XP_OFF);
    const bf16x8* wq8 = (const bf16x8*)(ws + WQ_OFF);

    int bid = blockIdx.x;
    int wg = (bid & 7) * 112 + (bid >> 3);     // XCD swizzle (896 % 8 == 0, bijective)
    int n = wg / 28, h0 = (wg % 28) * 2;

    int tid = threadIdx.x;
    int wv = tid >> 6, l = tid & 63;
    int l15 = l & 15, lq = l >> 4;
    int oc0 = (wv >> 1) * 128;
    int orow = wv & 1;

    __shared__ __hip_bfloat16 Xs[2 * 17408];   // 2 x [4][68][64] bf16
    __shared__ unsigned sdyn[16];
    if (tid < 16) sdyn[tid] = 0;

    int soff[9];
#pragma unroll
    for (int k = 0; k < 9; ++k) {
        int chunk = k * 256 + tid;
        int row = chunk / 544;
        int rem = chunk - row * 544;
        int wp = rem >> 3, u = rem & 7;
        int oct = u ^ (wp & 7);
        soff[k] = (row * WPAD + wp) * 256 + oct * 8;
    }
    int wavebase = tid & 192;
    size_t imgbase = ((size_t)n * HP + h0) * (size_t)(WPAD * 256);
    const bf16x8* wbase = wq8 + (size_t)(oc0 + l15) * 288 + lq;

    f32x4 acc[8][4];
#pragma unroll
    for (int i = 0; i < 8; ++i)
#pragma unroll
        for (int j = 0; j < 4; ++j) acc[i][j] = (f32x4){0.f, 0.f, 0.f, 0.f};

    auto STAGE = [&](int bufsel, int it) {
        const __hip_bfloat16* gb = Xp + imgbase + it * 64;
        char* lb = (char*)Xs + bufsel * 34816;
#pragma unroll
        for (int k = 0; k < 9; ++k) {
            if (k < 8 || tid < 128) {
                gload16(lb + (k * 256 + wavebase) * 16, gb + soff[k]);
            }
        }
    };

    auto LOADAF = [&](bf16x8* dst, int it_, int tap_, int ks_) {
#pragma unroll
        for (int i = 0; i < 8; ++i)
            dst[i] = wbase[(size_t)(i * 16) * 288 + tap_ * 32 + it_ * 8 + ks_ * 4];
    };

#define SUBLOOP(afc, tap_, ks_) do {                                            \
        const int dh_ = (tap_) / 3, dw_ = (tap_) % 3;                           \
        const int row_ = orow + dh_;                                            \
        __builtin_amdgcn_s_setprio(1);                                          \
        _Pragma("unroll")                                                       \
        for (int j = 0; j < 4; ++j) {                                           \
            int wp_ = j * 16 + l15 + dw_;                                       \
            int u_ = ((ks_) * 4 + lq) ^ (wp_ & 7);                              \
            bf16x8 bv = *(const bf16x8*)&Xb[((row_ * 68 + wp_) * 8 + u_) * 8];  \
            _Pragma("unroll")                                                   \
            for (int i = 0; i < 8; ++i)                                         \
                acc[i][j] = __builtin_amdgcn_mfma_f32_16x16x32_bf16(            \
                    afc[i], bv, acc[i][j], 0, 0, 0);                            \
        }                                                                       \
        __builtin_amdgcn_s_setprio(0);                                          \
    } while (0)

    bf16x8 afA[8], afB[8];
    LOADAF(afA, 0, 0, 0);
    STAGE(0, 0);
    __syncthreads();
    int buf = 0;
#pragma unroll 1
    for (int it = 0; it < 4; ++it) {
        if (it < 3) STAGE(buf ^ 1, it + 1);
        const __hip_bfloat16* Xb = Xs + buf * 17408;
        int itn = (it < 3) ? it + 1 : 3;
#pragma unroll
        for (int sp = 0; sp < 9; ++sp) {
            LOADAF(afB, it, sp, 1);          // prefetch (sp,ks=1)
            SUBLOOP(afA, sp, 0);
            if (sp < 8) LOADAF(afA, it, sp + 1, 0);
            else        LOADAF(afA, itn, 0, 0);   // cross iter boundary
            SUBLOOP(afB, sp, 1);
        }
        __syncthreads();
        buf ^= 1;
    }
#undef SUBLOOP

    int hrow = h0 + orow;
#pragma unroll
    for (int i = 0; i < 8; ++i) {
#pragma unroll
        for (int r = 0; r < 4; ++r) {
            int oc = oc0 + i * 16 + lq * 4 + r;
            float bi = hf[64 + oc];
            float m = 0.0f;
#pragma unroll
            for (int j = 0; j < 4; ++j) {
                int w = j * 16 + l15;
                float v = acc[i][j][r] + bi;
                if (w < 56) {
                    out[(((size_t)n * 256 + oc) * 56 + hrow) * 56 + w] = v;
                    m = fmaxf(m, fabsf(v));
                }
            }
#pragma unroll
            for (int s = 1; s < 16; s <<= 1) m = fmaxf(m, __shfl_xor(m, s));
            if (l15 == 0) atomicMax(&sdyn[bits[oc] & 15], __float_as_uint(m));
        }
    }
    __syncthreads();
    if (tid < 16 && sdyn[tid]) atomicMax(&hdr[4 + tid], sdyn[tid]);
}

__global__ void k_mfixed(const int* __restrict__ bits, char* ws) {
    unsigned* hdr = (unsigned*)ws;
    float* hf = (float*)ws;
    int tid = threadIdx.x;
    __shared__ float Mf[16], trs[16];
    if (tid < 16) {
        float dm = __uint_as_float(hdr[4 + tid]);
        int tr = (tid >= 1) ? ((1 << (tid - 1)) - 1) : 0;
        float M = 0.0f;
        if (dm > 0.0f) M = rintf(((float)tr / dm) * 65536.0f);
        Mf[tid] = M; trs[tid] = (float)tr;
    }
    __syncthreads();
    int oc = tid;
    int g = bits[oc] & 15;
    hf[320 + oc] = Mf[g];
    hf[576 + oc] = -trs[g] - 1.0f;
    hf[832 + oc] = trs[g];
}

__global__ __launch_bounds__(256) void k_requant(float* __restrict__ out, char* ws) {
    const float* hf = (const float*)ws;
    float4* o4 = (float4*)out;
    const int n4 = N_X / 4;
    const float inv64k = 1.0f / 65536.0f;
    for (int i = blockIdx.x * blockDim.x + threadIdx.x; i < n4; i += gridDim.x * blockDim.x) {
        int oc = (int)(((i * 4) / 3136) & 255);
        float M = hf[320 + oc], lo = hf[576 + oc], hi = hf[832 + oc];
        float4 v = o4[i];
        v.x = fminf(fmaxf(rintf(v.x * M * inv64k), lo), hi);
        v.y = fminf(fmaxf(rintf(v.y * M * inv64k), lo), hi);
        v.z = fminf(fmaxf(rintf(v.z * M * inv64k), lo), hi);
        v.w = fminf(fmaxf(rintf(v.w * M * inv64k), lo), hi);
        o4[i] = v;
    }
}

extern "C" void kernel_launch(void* const* d_in, const int* in_sizes, int n_in,
                              void* d_out, int out_size, void* d_ws, size_t ws_size,
                              hipStream_t stream) {
    const float* x      = (const float*)d_in[0];
    const float* weight = (const float*)d_in[1];
    const float* bias   = (const float*)d_in[2];
    const int*   bits   = (const int*)d_in[3];
    float* out = (float*)d_out;
    char* ws = (char*)d_ws;
    unsigned* hdr = (unsigned*)ws;

    k_init<<<1, 64, 0, stream>>>(hdr);
    k_minmax<<<2048, 256, 0, stream>>>((const float4*)x, N_X / 4, hdr);
    k_scalars<<<1, 1, 0, stream>>>(hdr);
    k_wquant<<<256, 256, 0, stream>>>(weight, bias, bits, ws);
    k_quantx<<<dim3(1, 58, 32), 256, 0, stream>>>(x, ws);
    k_conv<<<896, 256, 0, stream>>>(bits, out, ws);
    k_mfixed<<<1, 256, 0, stream>>>(bits, ws);
    k_requant<<<4096, 256, 0, stream>>>(out, ws);
}

// Round 6
// 561.149 us; speedup vs baseline: 1.1697x; 1.1697x over previous
//
#include <hip/hip_runtime.h>
#include <hip/hip_bf16.h>

typedef float f32x4 __attribute__((ext_vector_type(4)));
typedef __bf16 bf16x8 __attribute__((ext_vector_type(8)));

#define N_IMG 32
#define C_IN  256
#define HW    56
#define N_X   (N_IMG * C_IN * HW * HW)
#define HP    58
#define WPAD  68

static constexpr size_t WQ_OFF  = 8192;                 // bf16[256][2304]  [oc][tap][c]
static constexpr size_t XP_OFF  = 2097152;              // bf16[32][58][68][256]

__device__ __forceinline__ unsigned enc_f(float f) {
    unsigned u = __float_as_uint(f);
    return (u & 0x80000000u) ? ~u : (u | 0x80000000u);
}
__device__ __forceinline__ float dec_f(unsigned u) {
    u = (u & 0x80000000u) ? (u & 0x7FFFFFFFu) : ~u;
    return __uint_as_float(u);
}

__device__ __forceinline__ void gload16(void* lds, const void* g) {
    __builtin_amdgcn_global_load_lds(
        (const __attribute__((address_space(1))) unsigned int*)g,
        (__attribute__((address_space(3))) unsigned int*)lds, 16, 0, 0);
}

__global__ void k_init(unsigned* hdr) {
    int t = threadIdx.x;
    if (t == 0) hdr[0] = 0xFFFFFFFFu;
    if (t == 1) hdr[1] = 0u;
    if (t >= 4 && t < 20) hdr[t] = 0u;
}

__global__ __launch_bounds__(256) void k_minmax(const float4* __restrict__ x4, int n4, unsigned* hdr) {
    float mn = INFINITY, mx = -INFINITY;
    for (int i = blockIdx.x * blockDim.x + threadIdx.x; i < n4; i += gridDim.x * blockDim.x) {
        float4 v = x4[i];
        mn = fminf(mn, fminf(fminf(v.x, v.y), fminf(v.z, v.w)));
        mx = fmaxf(mx, fmaxf(fmaxf(v.x, v.y), fmaxf(v.z, v.w)));
    }
    for (int s = 32; s; s >>= 1) {
        mn = fminf(mn, __shfl_xor(mn, s));
        mx = fmaxf(mx, __shfl_xor(mx, s));
    }
    __shared__ float smn[4], smx[4];
    int l = threadIdx.x & 63, wv = threadIdx.x >> 6;
    if (l == 0) { smn[wv] = mn; smx[wv] = mx; }
    __syncthreads();
    if (threadIdx.x == 0) {
        mn = fminf(fminf(smn[0], smn[1]), fminf(smn[2], smn[3]));
        mx = fmaxf(fmaxf(smx[0], smx[1]), fmaxf(smx[2], smx[3]));
        atomicMin(&hdr[0], enc_f(mn));
        atomicMax(&hdr[1], enc_f(mx));
    }
}

__global__ void k_scalars(unsigned* hdr) {
    float xmin = dec_f(hdr[0]), xmax = dec_f(hdr[1]);
    float in_scale = (xmax - xmin) / 255.0f;
    float zp = rintf(-128.0f - xmin / in_scale);
    ((float*)hdr)[2] = in_scale;
    ((float*)hdr)[3] = zp;
}

__global__ __launch_bounds__(256) void k_wquant(const float* __restrict__ weight,
                                                const float* __restrict__ bias,
                                                const int* __restrict__ bits,
                                                char* ws) {
    float* hf = (float*)ws;
    __hip_bfloat16* Wq = (__hip_bfloat16*)(ws + WQ_OFF);
    int oc = blockIdx.x, tid = threadIdx.x;
    const float* wp = weight + ((size_t)oc * 256 + tid) * 9;
    float w9[9];
    float wm = 0.0f;
#pragma unroll
    for (int t = 0; t < 9; ++t) { w9[t] = wp[t]; wm = fmaxf(wm, fabsf(w9[t])); }
    for (int s = 32; s; s >>= 1) wm = fmaxf(wm, __shfl_xor(wm, s));
    __shared__ float red[4];
    __shared__ float s_wsc;
    int l = tid & 63, wv = tid >> 6;
    if (l == 0) red[wv] = wm;
    __syncthreads();
    int b = bits[oc];
    if (tid == 0) {
        float wmax = fmaxf(fmaxf(red[0], red[1]), fmaxf(red[2], red[3]));
        float qd = (float)((1 << b) - 1);
        float wsc = fmaxf(wmax * 2.0f / qd, 1e-9f);
        s_wsc = wsc;
        float in_scale = hf[2];
        hf[64 + oc] = rintf(bias[oc] / (in_scale * wsc));
    }
    __syncthreads();
    float wsc = s_wsc;
    float qmax = (float)((1 << (b - 1)) - 1);
    float qmin = -(float)(1 << (b - 1));
    size_t base = (size_t)oc * 2304;
#pragma unroll
    for (int t = 0; t < 9; ++t) {
        float q = rintf(w9[t] / wsc);
        q = fminf(fmaxf(q, qmin), qmax);
        Wq[base + t * 256 + tid] = __float2bfloat16(q);
    }
}

// quantize + NCHW -> padded NHWC bf16; writes all borders incl. wp 64..67, no memset
__global__ __launch_bounds__(256) void k_quantx(const float* __restrict__ x, char* ws) {
    const float* hf = (const float*)ws;
    float in_scale = hf[2], zp = hf[3];
    __hip_bfloat16* Xp = (__hip_bfloat16*)(ws + XP_OFF);
    int h = blockIdx.y, n = blockIdx.z;     // h is PADDED coord
    int tid = threadIdx.x;
    __shared__ float tx[32][65];
    int wA = tid & 63, cA = tid >> 6;      // read: 64 w x 4 c (one c per wave)
    int wW = tid >> 2, cq = tid & 3;       // write: 64 wp x 4 c-octs
    int xh = h - 1;
    bool hok = (xh >= 0 && xh < 56);
    int xw = wA - 1;
    bool ok = hok && (xw >= 0 && xw < 56);
    size_t rowbase = ((size_t)n * HP + h) * WPAD * 256;
    for (int ct = 0; ct < 8; ++ct) {
#pragma unroll
        for (int cs = 0; cs < 8; ++cs) {
            int c = ct * 32 + cs * 4 + cA;
            float q = 0.0f;
            if (ok) {
                float v = x[(((size_t)n * 256 + c) * 56 + xh) * 56 + xw];
                float xi = rintf(v / in_scale + zp);
                xi = fminf(fmaxf(xi, -128.0f), 127.0f);
                q = xi - zp;
            }
            tx[cs * 4 + cA][wA] = q;
        }
        __syncthreads();
        {
            __hip_bfloat16 tmp[8];
#pragma unroll
            for (int k2 = 0; k2 < 8; ++k2) tmp[k2] = __float2bfloat16(tx[cq * 8 + k2][wW]);
            *(uint4*)&Xp[rowbase + (size_t)wW * 256 + ct * 32 + cq * 8] = *(uint4*)tmp;
        }
        if (tid < 16) {   // zero-fill wp 64..67
            int wpz = 64 + (tid >> 2), cqz = tid & 3;
            uint4 z = {0, 0, 0, 0};
            *(uint4*)&Xp[rowbase + (size_t)wpz * 256 + ct * 32 + cqz * 8] = z;
        }
        __syncthreads();
    }
}

// conv: workgroup = 256 oc x 2 output rows; 4 waves = 4 oc-QUARTERS, each wave
// computes its 64 oc over BOTH rows (128 px): acc[4][8]. Halves per-wave weight
// fetch vs i8/j4 and removes row-wave weight redundancy. X staged via
// global_load_lds (double-buffered, source-side XOR swizzle).
__global__ __launch_bounds__(256, 2) void k_conv(const int* __restrict__ bits,
                                                 float* __restrict__ out, char* ws) {
    const float* hf = (const float*)ws;
    unsigned* hdr = (unsigned*)ws;
    const __hip_bfloat16* Xp = (const __hip_bfloat16*)(ws + XP_OFF);
    const bf16x8* wq8 = (const bf16x8*)(ws + WQ_OFF);

    int bid = blockIdx.x;
    int wg = (bid & 7) * 112 + (bid >> 3);     // XCD swizzle (896 % 8 == 0, bijective)
    int n = wg / 28, h0 = (wg % 28) * 2;

    int tid = threadIdx.x;
    int wv = tid >> 6, l = tid & 63;
    int l15 = l & 15, lq = l >> 4;
    int oc0 = wv * 64;                         // oc quarter per wave

    __shared__ __hip_bfloat16 Xs[2 * 17408];   // 2 x [4][68][64] bf16
    __shared__ unsigned sdyn[16];
    if (tid < 16) sdyn[tid] = 0;

    int soff[9];
#pragma unroll
    for (int k = 0; k < 9; ++k) {
        int chunk = k * 256 + tid;
        int row = chunk / 544;
        int rem = chunk - row * 544;
        int wp = rem >> 3, u = rem & 7;
        int oct = u ^ (wp & 7);
        soff[k] = (row * WPAD + wp) * 256 + oct * 8;
    }
    int wavebase = tid & 192;
    size_t imgbase = ((size_t)n * HP + h0) * (size_t)(WPAD * 256);
    const bf16x8* wbase = wq8 + (size_t)(oc0 + l15) * 288 + lq;

    f32x4 acc[4][8];
#pragma unroll
    for (int i = 0; i < 4; ++i)
#pragma unroll
        for (int j = 0; j < 8; ++j) acc[i][j] = (f32x4){0.f, 0.f, 0.f, 0.f};

    auto STAGE = [&](int bufsel, int it) {
        const __hip_bfloat16* gb = Xp + imgbase + it * 64;
        char* lb = (char*)Xs + bufsel * 34816;
#pragma unroll
        for (int k = 0; k < 9; ++k) {
            if (k < 8 || tid < 128) {
                gload16(lb + (k * 256 + wavebase) * 16, gb + soff[k]);
            }
        }
    };

    STAGE(0, 0);
    __syncthreads();
    int buf = 0;
#pragma unroll 1
    for (int it = 0; it < 4; ++it) {
        if (it < 3) STAGE(buf ^ 1, it + 1);
        const __hip_bfloat16* Xb = Xs + buf * 17408;
#pragma unroll
        for (int dh = 0; dh < 3; ++dh) {
#pragma unroll
            for (int dw = 0; dw < 3; ++dw) {
                int tap = dh * 3 + dw;
#pragma unroll
                for (int ks = 0; ks < 2; ++ks) {
                    bf16x8 af[4];
#pragma unroll
                    for (int i = 0; i < 4; ++i)
                        af[i] = wbase[(size_t)(i * 16) * 288 + tap * 32 +
                                      it * 8 + ks * 4];
#pragma unroll
                    for (int j = 0; j < 8; ++j) {
                        int row = (j >> 2) + dh;               // output row (j>>2) + dh
                        int wp = (j & 3) * 16 + l15 + dw;
                        int u = (ks * 4 + lq) ^ (wp & 7);
                        bf16x8 bv = *(const bf16x8*)&Xb[((row * 68 + wp) * 8 + u) * 8];
#pragma unroll
                        for (int i = 0; i < 4; ++i)
                            acc[i][j] = __builtin_amdgcn_mfma_f32_16x16x32_bf16(
                                af[i], bv, acc[i][j], 0, 0, 0);
                    }
                }
            }
        }
        __syncthreads();
        buf ^= 1;
    }

    // epilogue: + b_int, store, per-group max|acc|
#pragma unroll
    for (int i = 0; i < 4; ++i) {
#pragma unroll
        for (int r = 0; r < 4; ++r) {
            int oc = oc0 + i * 16 + lq * 4 + r;
            float bi = hf[64 + oc];
            float m = 0.0f;
#pragma unroll
            for (int j = 0; j < 8; ++j) {
                int w = (j & 3) * 16 + l15;
                int hrow = h0 + (j >> 2);
                float v = acc[i][j][r] + bi;
                if (w < 56) {
                    out[(((size_t)n * 256 + oc) * 56 + hrow) * 56 + w] = v;
                    m = fmaxf(m, fabsf(v));
                }
            }
#pragma unroll
            for (int s = 1; s < 16; s <<= 1) m = fmaxf(m, __shfl_xor(m, s));
            if (l15 == 0) atomicMax(&sdyn[bits[oc] & 15], __float_as_uint(m));
        }
    }
    __syncthreads();
    if (tid < 16 && sdyn[tid]) atomicMax(&hdr[4 + tid], sdyn[tid]);
}

__global__ void k_mfixed(const int* __restrict__ bits, char* ws) {
    unsigned* hdr = (unsigned*)ws;
    float* hf = (float*)ws;
    int tid = threadIdx.x;
    __shared__ float Mf[16], trs[16];
    if (tid < 16) {
        float dm = __uint_as_float(hdr[4 + tid]);
        int tr = (tid >= 1) ? ((1 << (tid - 1)) - 1) : 0;
        float M = 0.0f;
        if (dm > 0.0f) M = rintf(((float)tr / dm) * 65536.0f);
        Mf[tid] = M; trs[tid] = (float)tr;
    }
    __syncthreads();
    int oc = tid;
    int g = bits[oc] & 15;
    hf[320 + oc] = Mf[g];
    hf[576 + oc] = -trs[g] - 1.0f;
    hf[832 + oc] = trs[g];
}

__global__ __launch_bounds__(256) void k_requant(float* __restrict__ out, char* ws) {
    const float* hf = (const float*)ws;
    float4* o4 = (float4*)out;
    const int n4 = N_X / 4;
    const float inv64k = 1.0f / 65536.0f;
    for (int i = blockIdx.x * blockDim.x + threadIdx.x; i < n4; i += gridDim.x * blockDim.x) {
        int oc = (int)(((i * 4) / 3136) & 255);
        float M = hf[320 + oc], lo = hf[576 + oc], hi = hf[832 + oc];
        float4 v = o4[i];
        v.x = fminf(fmaxf(rintf(v.x * M * inv64k), lo), hi);
        v.y = fminf(fmaxf(rintf(v.y * M * inv64k), lo), hi);
        v.z = fminf(fmaxf(rintf(v.z * M * inv64k), lo), hi);
        v.w = fminf(fmaxf(rintf(v.w * M * inv64k), lo), hi);
        o4[i] = v;
    }
}

extern "C" void kernel_launch(void* const* d_in, const int* in_sizes, int n_in,
                              void* d_out, int out_size, void* d_ws, size_t ws_size,
                              hipStream_t stream) {
    const float* x      = (const float*)d_in[0];
    const float* weight = (const float*)d_in[1];
    const float* bias   = (const float*)d_in[2];
    const int*   bits   = (const int*)d_in[3];
    float* out = (float*)d_out;
    char* ws = (char*)d_ws;
    unsigned* hdr = (unsigned*)ws;

    k_init<<<1, 64, 0, stream>>>(hdr);
    k_minmax<<<2048, 256, 0, stream>>>((const float4*)x, N_X / 4, hdr);
    k_scalars<<<1, 1, 0, stream>>>(hdr);
    k_wquant<<<256, 256, 0, stream>>>(weight, bias, bits, ws);
    k_quantx<<<dim3(1, 58, 32), 256, 0, stream>>>(x, ws);
    k_conv<<<896, 256, 0, stream>>>(bits, out, ws);
    k_mfixed<<<1, 256, 0, stream>>>(bits, ws);
    k_requant<<<4096, 256, 0, stream>>>(out, ws);
}

// Round 7
// 428.852 us; speedup vs baseline: 1.5306x; 1.3085x over previous
//
#include <hip/hip_runtime.h>
#include <hip/hip_bf16.h>

typedef float f32x4 __attribute__((ext_vector_type(4)));
typedef __bf16 bf16x8 __attribute__((ext_vector_type(8)));

#define N_IMG 32
#define C_IN  256
#define HW    56
#define N_X   (N_IMG * C_IN * HW * HW)
#define HP    58
#define WPAD  68

static constexpr size_t WQ_OFF  = 8192;                 // bf16[256][2304]  [oc][tap][c]
static constexpr size_t XP_OFF  = 2097152;              // bf16[32][58][68][256]

// hdr: [0] xmin_enc [1] xmax_enc [4..19] dynmax per bit
// hf:  [64..319] b_int per oc

__device__ __forceinline__ unsigned enc_f(float f) {
    unsigned u = __float_as_uint(f);
    return (u & 0x80000000u) ? ~u : (u | 0x80000000u);
}
__device__ __forceinline__ float dec_f(unsigned u) {
    u = (u & 0x80000000u) ? (u & 0x7FFFFFFFu) : ~u;
    return __uint_as_float(u);
}

__device__ __forceinline__ void gload16(void* lds, const void* g) {
    __builtin_amdgcn_global_load_lds(
        (const __attribute__((address_space(1))) unsigned int*)g,
        (__attribute__((address_space(3))) unsigned int*)lds, 16, 0, 0);
}

__global__ void k_init(unsigned* hdr) {
    int t = threadIdx.x;
    if (t == 0) hdr[0] = 0xFFFFFFFFu;
    if (t == 1) hdr[1] = 0u;
    if (t >= 4 && t < 20) hdr[t] = 0u;
}

__global__ __launch_bounds__(256) void k_minmax(const float4* __restrict__ x4, int n4, unsigned* hdr) {
    float mn = INFINITY, mx = -INFINITY;
    for (int i = blockIdx.x * blockDim.x + threadIdx.x; i < n4; i += gridDim.x * blockDim.x) {
        float4 v = x4[i];
        mn = fminf(mn, fminf(fminf(v.x, v.y), fminf(v.z, v.w)));
        mx = fmaxf(mx, fmaxf(fmaxf(v.x, v.y), fmaxf(v.z, v.w)));
    }
    for (int s = 32; s; s >>= 1) {
        mn = fminf(mn, __shfl_xor(mn, s));
        mx = fmaxf(mx, __shfl_xor(mx, s));
    }
    __shared__ float smn[4], smx[4];
    int l = threadIdx.x & 63, wv = threadIdx.x >> 6;
    if (l == 0) { smn[wv] = mn; smx[wv] = mx; }
    __syncthreads();
    if (threadIdx.x == 0) {
        mn = fminf(fminf(smn[0], smn[1]), fminf(smn[2], smn[3]));
        mx = fmaxf(fmaxf(smx[0], smx[1]), fmaxf(smx[2], smx[3]));
        atomicMin(&hdr[0], enc_f(mn));
        atomicMax(&hdr[1], enc_f(mx));
    }
}

__global__ __launch_bounds__(256) void k_wquant(const float* __restrict__ weight,
                                                const float* __restrict__ bias,
                                                const int* __restrict__ bits,
                                                char* ws) {
    float* hf = (float*)ws;
    unsigned* hdr = (unsigned*)ws;
    __hip_bfloat16* Wq = (__hip_bfloat16*)(ws + WQ_OFF);
    int oc = blockIdx.x, tid = threadIdx.x;
    const float* wp = weight + ((size_t)oc * 256 + tid) * 9;
    float w9[9];
    float wm = 0.0f;
#pragma unroll
    for (int t = 0; t < 9; ++t) { w9[t] = wp[t]; wm = fmaxf(wm, fabsf(w9[t])); }
    for (int s = 32; s; s >>= 1) wm = fmaxf(wm, __shfl_xor(wm, s));
    __shared__ float red[4];
    __shared__ float s_wsc;
    int l = tid & 63, wv = tid >> 6;
    if (l == 0) red[wv] = wm;
    __syncthreads();
    int b = bits[oc];
    if (tid == 0) {
        float wmax = fmaxf(fmaxf(red[0], red[1]), fmaxf(red[2], red[3]));
        float qd = (float)((1 << b) - 1);
        float wsc = fmaxf(wmax * 2.0f / qd, 1e-9f);
        s_wsc = wsc;
        float xmin = dec_f(hdr[0]), xmax = dec_f(hdr[1]);
        float in_scale = (xmax - xmin) / 255.0f;
        hf[64 + oc] = rintf(bias[oc] / (in_scale * wsc));
    }
    __syncthreads();
    float wsc = s_wsc;
    float qmax = (float)((1 << (b - 1)) - 1);
    float qmin = -(float)(1 << (b - 1));
    size_t base = (size_t)oc * 2304;
#pragma unroll
    for (int t = 0; t < 9; ++t) {
        float q = rintf(w9[t] / wsc);
        q = fminf(fmaxf(q, qmin), qmax);
        Wq[base + t * 256 + tid] = __float2bfloat16(q);
    }
}

// quantize + NCHW -> padded NHWC bf16; writes all borders incl. wp 64..67, no memset
__global__ __launch_bounds__(256) void k_quantx(const float* __restrict__ x, char* ws) {
    unsigned* hdr = (unsigned*)ws;
    float xmin = dec_f(hdr[0]), xmax = dec_f(hdr[1]);
    float in_scale = (xmax - xmin) / 255.0f;
    float zp = rintf(-128.0f - xmin / in_scale);
    __hip_bfloat16* Xp = (__hip_bfloat16*)(ws + XP_OFF);
    int h = blockIdx.y, n = blockIdx.z;     // h is PADDED coord
    int tid = threadIdx.x;
    __shared__ float tx[32][65];
    int wA = tid & 63, cA = tid >> 6;      // read: 64 w x 4 c (one c per wave)
    int wW = tid >> 2, cq = tid & 3;       // write: 64 wp x 4 c-octs
    int xh = h - 1;
    bool hok = (xh >= 0 && xh < 56);
    int xw = wA - 1;
    bool ok = hok && (xw >= 0 && xw < 56);
    size_t rowbase = ((size_t)n * HP + h) * WPAD * 256;
    for (int ct = 0; ct < 8; ++ct) {
#pragma unroll
        for (int cs = 0; cs < 8; ++cs) {
            int c = ct * 32 + cs * 4 + cA;
            float q = 0.0f;
            if (ok) {
                float v = x[(((size_t)n * 256 + c) * 56 + xh) * 56 + xw];
                float xi = rintf(v / in_scale + zp);
                xi = fminf(fmaxf(xi, -128.0f), 127.0f);
                q = xi - zp;
            }
            tx[cs * 4 + cA][wA] = q;
        }
        __syncthreads();
        {
            __hip_bfloat16 tmp[8];
#pragma unroll
            for (int k2 = 0; k2 < 8; ++k2) tmp[k2] = __float2bfloat16(tx[cq * 8 + k2][wW]);
            *(uint4*)&Xp[rowbase + (size_t)wW * 256 + ct * 32 + cq * 8] = *(uint4*)tmp;
        }
        if (tid < 16) {   // zero-fill wp 64..67
            int wpz = 64 + (tid >> 2), cqz = tid & 3;
            uint4 z = {0, 0, 0, 0};
            *(uint4*)&Xp[rowbase + (size_t)wpz * 256 + ct * 32 + cqz * 8] = z;
        }
        __syncthreads();
    }
}

// conv, canonical both-operands-in-LDS implicit GEMM.
// Block: 512 thr / 8 waves = (2 oc-halves) x (4 output rows). 256 oc x 4 rows x 64 w.
// Per c-chunk(64): stage X rows h0..h0+5 ([6][68][64] bf16, 52KB, single-buffered,
// serves all 9 taps), then 9 taps each staging W[256][64] (32KB, double-buffered).
// Both staged via global_load_lds with source-side XOR swizzle (conflict-free reads).
__global__ __launch_bounds__(512, 2) void k_conv(const int* __restrict__ bits,
                                                 float* __restrict__ out, char* ws) {
    const float* hf = (const float*)ws;
    unsigned* hdr = (unsigned*)ws;
    const __hip_bfloat16* Xp = (const __hip_bfloat16*)(ws + XP_OFF);
    const __hip_bfloat16* Wq = (const __hip_bfloat16*)(ws + WQ_OFF);

    int bid = blockIdx.x;
    int wg = (bid & 7) * 56 + (bid >> 3);      // XCD swizzle (448 % 8 == 0, bijective)
    int n = wg / 14, h0 = (wg % 14) * 4;

    int tid = threadIdx.x;
    int l = tid & 63;
    int l15 = l & 15, lq = l >> 4;
    int wv = tid >> 6;
    int wm = wv >> 2, wn = wv & 3;             // oc-half, output row
    int oc0 = wm * 128;

    __shared__ __hip_bfloat16 Xs[6 * 68 * 64];     // 52224 B
    __shared__ __hip_bfloat16 Wsb[2][256 * 64];    // 2 x 32768 B
    __shared__ unsigned sdyn[16];
    if (tid < 16) sdyn[tid] = 0;

    // X staging: 3264 16B-chunks = 6*512 + 192
    int soffX[7];
#pragma unroll
    for (int k = 0; k < 7; ++k) {
        int q = k * 512 + tid;
        int row = q / 544;                     // 544 chunks per row (68 wp x 8 octs)
        int rem = q - row * 544;
        int wp = rem >> 3, u = rem & 7;
        soffX[k] = (row * WPAD + wp) * 256 + (u ^ (wp & 7)) * 8;
    }
    // W staging: 2048 16B-chunks = 4*512
    int soffW[4];
#pragma unroll
    for (int k = 0; k < 4; ++k) {
        int q = k * 512 + tid;
        int oc = q >> 3, u = q & 7;
        soffW[k] = oc * 2304 + (u ^ (oc & 7)) * 8;
    }
    int wavebase = tid & 448;
    size_t xbase = ((size_t)n * HP + h0) * (size_t)(WPAD * 256);

    f32x4 acc[8][4];
#pragma unroll
    for (int i = 0; i < 8; ++i)
#pragma unroll
        for (int j = 0; j < 4; ++j) acc[i][j] = (f32x4){0.f, 0.f, 0.f, 0.f};

    auto STAGE_X = [&](int cc) {
        const __hip_bfloat16* gb = Xp + xbase + cc;
#pragma unroll
        for (int k = 0; k < 7; ++k) {
            if (k < 6 || tid < 192)
                gload16((char*)Xs + (k * 512 + wavebase) * 16, gb + soffX[k]);
        }
    };
    auto STAGE_W = [&](int bufsel, int tap, int cc) {
        const __hip_bfloat16* gb = Wq + tap * 256 + cc;
        char* dst = (char*)Wsb[bufsel];
#pragma unroll
        for (int k = 0; k < 4; ++k)
            gload16(dst + (k * 512 + wavebase) * 16, gb + soffW[k]);
    };

#pragma unroll 1
    for (int cc4 = 0; cc4 < 4; ++cc4) {
        int cc = cc4 * 64;
        STAGE_X(cc);
        STAGE_W(0, 0, cc);
        __syncthreads();                       // X + W(tap0) landed
#pragma unroll
        for (int tap = 0; tap < 9; ++tap) {
            if (tap < 8) STAGE_W((tap + 1) & 1, tap + 1, cc);   // prefetch next tap
            const int dh = tap / 3, dw = tap % 3;
            const __hip_bfloat16* Wb = Wsb[tap & 1];
            __builtin_amdgcn_s_setprio(1);
#pragma unroll
            for (int ks = 0; ks < 2; ++ks) {
                bf16x8 af[8];
#pragma unroll
                for (int i = 0; i < 8; ++i) {
                    int ocl = oc0 + i * 16 + l15;
                    af[i] = *(const bf16x8*)&Wb[ocl * 64 + ((ks * 4 + lq) ^ (ocl & 7)) * 8];
                }
#pragma unroll
                for (int j = 0; j < 4; ++j) {
                    int row = wn + dh;
                    int wp = j * 16 + l15 + dw;
                    int u = (ks * 4 + lq) ^ (wp & 7);
                    bf16x8 bv = *(const bf16x8*)&Xs[(row * 68 + wp) * 64 + u * 8];
#pragma unroll
                    for (int i = 0; i < 8; ++i)
                        acc[i][j] = __builtin_amdgcn_mfma_f32_16x16x32_bf16(
                            af[i], bv, acc[i][j], 0, 0, 0);
                }
            }
            __builtin_amdgcn_s_setprio(0);
            __syncthreads();                   // drains W(tap+1); protects read buffer
        }
    }

    // epilogue: + b_int, store, per-group max|acc|
    int hrow = h0 + wn;
#pragma unroll
    for (int i = 0; i < 8; ++i) {
#pragma unroll
        for (int r = 0; r < 4; ++r) {
            int oc = oc0 + i * 16 + lq * 4 + r;
            float bi = hf[64 + oc];
            float m = 0.0f;
#pragma unroll
            for (int j = 0; j < 4; ++j) {
                int w = j * 16 + l15;
                float v = acc[i][j][r] + bi;
                if (w < 56) {
                    out[(((size_t)n * 256 + oc) * 56 + hrow) * 56 + w] = v;
                    m = fmaxf(m, fabsf(v));
                }
            }
#pragma unroll
            for (int s = 1; s < 16; s <<= 1) m = fmaxf(m, __shfl_xor(m, s));
            if (l15 == 0) atomicMax(&sdyn[bits[oc] & 15], __float_as_uint(m));
        }
    }
    __syncthreads();
    if (tid < 16 && sdyn[tid]) atomicMax(&hdr[4 + tid], sdyn[tid]);
}

// requant with fused M_fixed computation (per-block LUT from hdr dynmax)
__global__ __launch_bounds__(256) void k_requant(float* __restrict__ out,
                                                 const int* __restrict__ bits, char* ws) {
    unsigned* hdr = (unsigned*)ws;
    __shared__ float Mf16[16], trs16[16];
    __shared__ float sM[256], sTr[256];
    int tid = threadIdx.x;
    if (tid < 16) {
        float dm = __uint_as_float(hdr[4 + tid]);
        int tr = (tid >= 1) ? ((1 << (tid - 1)) - 1) : 0;
        float M = 0.0f;
        if (dm > 0.0f) M = rintf(((float)tr / dm) * 65536.0f);
        Mf16[tid] = M; trs16[tid] = (float)tr;
    }
    __syncthreads();
    {
        int g = bits[tid] & 15;
        sM[tid] = Mf16[g];
        sTr[tid] = trs16[g];
    }
    __syncthreads();
    float4* o4 = (float4*)out;
    const int n4 = N_X / 4;
    const float inv64k = 1.0f / 65536.0f;
    for (int i = blockIdx.x * blockDim.x + threadIdx.x; i < n4; i += gridDim.x * blockDim.x) {
        int oc = (int)(((i * 4) / 3136) & 255);
        float M = sM[oc], hi = sTr[oc], lo = -hi - 1.0f;
        float4 v = o4[i];
        v.x = fminf(fmaxf(rintf(v.x * M * inv64k), lo), hi);
        v.y = fminf(fmaxf(rintf(v.y * M * inv64k), lo), hi);
        v.z = fminf(fmaxf(rintf(v.z * M * inv64k), lo), hi);
        v.w = fminf(fmaxf(rintf(v.w * M * inv64k), lo), hi);
        o4[i] = v;
    }
}

extern "C" void kernel_launch(void* const* d_in, const int* in_sizes, int n_in,
                              void* d_out, int out_size, void* d_ws, size_t ws_size,
                              hipStream_t stream) {
    const float* x      = (const float*)d_in[0];
    const float* weight = (const float*)d_in[1];
    const float* bias   = (const float*)d_in[2];
    const int*   bits   = (const int*)d_in[3];
    float* out = (float*)d_out;
    char* ws = (char*)d_ws;
    unsigned* hdr = (unsigned*)ws;

    k_init<<<1, 64, 0, stream>>>(hdr);
    k_minmax<<<2048, 256, 0, stream>>>((const float4*)x, N_X / 4, hdr);
    k_wquant<<<256, 256, 0, stream>>>(weight, bias, bits, ws);
    k_quantx<<<dim3(1, 58, 32), 256, 0, stream>>>(x, ws);
    k_conv<<<448, 512, 0, stream>>>(bits, out, ws);
    k_requant<<<4096, 256, 0, stream>>>(out, bits, ws);
}